// Round 3
// baseline (936.517 us; speedup 1.0000x reference)
//
#include <hip/hip_runtime.h>

// ---------------------------------------------------------------------------
// GFGCN round 3: register-direct MFMA GEMMs, split-K=16, VGPR capped at 128
// so the full 1024-block grid is co-resident (4 blocks/CU, 16 waves/CU).
//
// Frag layouts (m89/m91-verified):
//   A-frag : lane holds A[m = l15][k = quad*8 + j]   (16 B contiguous/lane)
//   B-frag : lane holds B[k = quad*8 + j][n = l15]   == Bt[n][k..k+7]
//   C/D    : reg r -> row = quad*4 + r, col = l15    (rows contiguous)
// ---------------------------------------------------------------------------

typedef __attribute__((ext_vector_type(4))) float  f32x4;
typedef __attribute__((ext_vector_type(8))) __bf16 bf16x8;
typedef __attribute__((ext_vector_type(4))) __bf16 bf16x4;

__global__ void cvt_f32_bf16(const float4* __restrict__ in,
                             bf16x4* __restrict__ out, int n4) {
    int i  = blockIdx.x * blockDim.x + threadIdx.x;
    int st = gridDim.x * blockDim.x;
    for (; i < n4; i += st) {
        float4 v = in[i];
        bf16x4 o;
        o[0] = (__bf16)v.x; o[1] = (__bf16)v.y;
        o[2] = (__bf16)v.z; o[3] = (__bf16)v.w;
        out[i] = o;
    }
}

__global__ void cvt_transpose(const float* __restrict__ W,
                              __bf16* __restrict__ Wt, int Kd, int Md) {
    int i = blockIdx.x * blockDim.x + threadIdx.x;
    if (i < Kd * Md) {
        int k = i / Md, m = i % Md;
        Wt[(size_t)m * Kd + k] = (__bf16)W[i];
    }
}

// ---------------------------------------------------------------------------
// Register-direct GEMM. Block = 4 waves stacked in M; wave covers
// (MF*16) rows x (NF*16) cols. BM = 64*MF, BN = 16*NF.
// grid: x = m-tile, y = n-tile, z = K-split.
// OUTMODE 0: fp32 partial, t-layout P[z][col][row] (rows contiguous, f32x4)
// OUTMODE 1: bf16 row-major out[row*ldO + col] (scattered 2B, small data)
// ---------------------------------------------------------------------------
template<int MF, int NF, int OUTMODE>
__global__ __launch_bounds__(256, 4)   // cap at 128 VGPR -> 4 blocks/CU
void gemm_rd(const __bf16* __restrict__ A, const __bf16* __restrict__ Bt,
             void* __restrict__ out, int K, int Kchunk, int Mtot, int Ntot)
{
    const int lane = threadIdx.x & 63;
    const int w    = threadIdx.x >> 6;
    const int l15  = lane & 15;
    const int quad = lane >> 4;

    const int m_base = blockIdx.x * (64 * MF) + w * (16 * MF);
    const int n_base = blockIdx.y * (16 * NF);
    const int kstart = blockIdx.z * Kchunk;

    const __bf16* Ap[MF];
    #pragma unroll
    for (int mf = 0; mf < MF; mf++)
        Ap[mf] = A + (size_t)(m_base + mf * 16 + l15) * K + kstart + quad * 8;
    const __bf16* Bp[NF];
    #pragma unroll
    for (int nf = 0; nf < NF; nf++)
        Bp[nf] = Bt + (size_t)(n_base + nf * 16 + l15) * K + kstart + quad * 8;

    f32x4 acc[MF][NF];
    #pragma unroll
    for (int mf = 0; mf < MF; mf++)
        #pragma unroll
        for (int nf = 0; nf < NF; nf++)
            acc[mf][nf] = (f32x4){0.f, 0.f, 0.f, 0.f};

    for (int ks = 0; ks < Kchunk; ks += 32) {
        bf16x8 a[MF], b[NF];
        #pragma unroll
        for (int mf = 0; mf < MF; mf++) a[mf] = *(const bf16x8*)(Ap[mf] + ks);
        #pragma unroll
        for (int nf = 0; nf < NF; nf++) b[nf] = *(const bf16x8*)(Bp[nf] + ks);
        #pragma unroll
        for (int mf = 0; mf < MF; mf++)
            #pragma unroll
            for (int nf = 0; nf < NF; nf++)
                acc[mf][nf] = __builtin_amdgcn_mfma_f32_16x16x32_bf16(
                    a[mf], b[nf], acc[mf][nf], 0, 0, 0);
    }

    if (OUTMODE == 0) {
        float* P = (float*)out + (size_t)blockIdx.z * Mtot * Ntot;
        #pragma unroll
        for (int mf = 0; mf < MF; mf++) {
            const int rowb = m_base + mf * 16 + quad * 4;
            #pragma unroll
            for (int nf = 0; nf < NF; nf++) {
                const int col = n_base + nf * 16 + l15;
                *(f32x4*)(P + (size_t)col * Mtot + rowb) = acc[mf][nf];
            }
        }
    } else {
        __bf16* O = (__bf16*)out;
        #pragma unroll
        for (int mf = 0; mf < MF; mf++) {
            const int rowb = m_base + mf * 16 + quad * 4;
            #pragma unroll
            for (int nf = 0; nf < NF; nf++) {
                const int col = n_base + nf * 16 + l15;
                #pragma unroll
                for (int r = 0; r < 4; r++)
                    O[(size_t)(rowb + r) * Ntot + col] = (__bf16)acc[mf][nf][r];
            }
        }
    }
}

// ---- sum SP split-partials -> bf16 t-layout Y[f][node] ----
__global__ void reduce_partials(const float* __restrict__ P,
                                __bf16* __restrict__ Y, int total4,
                                int SP, int MN) {
    int i = blockIdx.x * blockDim.x + threadIdx.x;
    if (i >= total4) return;
    size_t base = (size_t)i * 4;
    float4 s = *(const float4*)(P + base);
    for (int sp = 1; sp < SP; sp++) {
        float4 v = *(const float4*)(P + (size_t)sp * MN + base);
        s.x += v.x; s.y += v.y; s.z += v.z; s.w += v.w;
    }
    bf16x4 o; o[0] = (__bf16)s.x; o[1] = (__bf16)s.y;
    o[2] = (__bf16)s.z; o[3] = (__bf16)s.w;
    *(bf16x4*)(Y + base) = o;
}

// ---- combine: out[node][f] = act(h0*Y0 + h1*Y1 + h2*sum(P) + b[f]) ----
template<int RELU, int F32OUT>
__global__ void combine_out(const float* __restrict__ P,
                            const __bf16* __restrict__ Y0t,
                            const __bf16* __restrict__ Y1t,
                            const float* __restrict__ h,
                            const float* __restrict__ bias,
                            void* __restrict__ outp,
                            int F, int SP) {
    const int i = blockIdx.x * blockDim.x + threadIdx.x;  // (f, node4)
    const int total = F * 2048;
    if (i >= total) return;
    const int f  = i >> 11;
    const int n4 = i & 2047;
    const size_t base = (size_t)f * 8192 + (size_t)n4 * 4;
    const int MN = F * 8192;

    float4 s = *(const float4*)(P + base);
    for (int sp = 1; sp < SP; sp++) {
        float4 v = *(const float4*)(P + (size_t)sp * MN + base);
        s.x += v.x; s.y += v.y; s.z += v.z; s.w += v.w;
    }
    bf16x4 y0 = *(const bf16x4*)(Y0t + base);
    bf16x4 y1 = *(const bf16x4*)(Y1t + base);
    const float h0 = h[0], h1 = h[1], h2 = h[2], bb = bias[f];

    float v[4] = {s.x, s.y, s.z, s.w};
    #pragma unroll
    for (int r = 0; r < 4; r++) {
        float x = h0 * (float)y0[r] + h1 * (float)y1[r] + h2 * v[r] + bb;
        if (RELU) x = fmaxf(x, 0.0f);
        v[r] = x;
    }
    const int node = n4 * 4;
    if (F32OUT) {
        float* O = (float*)outp;
        #pragma unroll
        for (int r = 0; r < 4; r++) O[(size_t)(node + r) * F + f] = v[r];
    } else {
        __bf16* O = (__bf16*)outp;
        #pragma unroll
        for (int r = 0; r < 4; r++) O[(size_t)(node + r) * F + f] = (__bf16)v[r];
    }
}

extern "C" void kernel_launch(void* const* d_in, const int* in_sizes, int n_in,
                              void* d_out, int out_size, void* d_ws, size_t ws_size,
                              hipStream_t stream) {
    const float* S  = (const float*)d_in[0];
    const float* X  = (const float*)d_in[1];
    const float* W1 = (const float*)d_in[2];
    const float* h1 = (const float*)d_in[3];
    const float* b1 = (const float*)d_in[4];
    const float* W2 = (const float*)d_in[5];
    const float* h2 = (const float*)d_in[6];
    const float* b2 = (const float*)d_in[7];
    const float* W3 = (const float*)d_in[8];
    const float* h3 = (const float*)d_in[9];
    const float* b3 = (const float*)d_in[10];
    float* out = (float*)d_out;

    const int Nn = 8192, IN = 512, HID = 128, OUT = 64;

    char* ws = (char*)d_ws;
    size_t off = 0;
    auto carve = [&](size_t bytes) -> void* {
        void* p = ws + off;
        off += (bytes + 255) & ~(size_t)255;
        return p;
    };
    __bf16* Sb  = (__bf16*)carve((size_t)Nn * Nn  * 2);   // 134.2 MB
    __bf16* Xb  = (__bf16*)carve((size_t)Nn * IN  * 2);   // 8.4 MB
    __bf16* W1t = (__bf16*)carve((size_t)IN  * HID * 2);
    __bf16* W2t = (__bf16*)carve((size_t)HID * HID * 2);
    __bf16* W3t = (__bf16*)carve((size_t)HID * OUT * 2);
    __bf16* Y0t = (__bf16*)carve((size_t)HID * Nn * 2);   // [F][8192]
    __bf16* Y1t = (__bf16*)carve((size_t)HID * Nn * 2);
    __bf16* Act = (__bf16*)carve((size_t)Nn * HID * 2);   // [node][F]
    size_t  base = off;

    // split-K: want 16 (grid 64x16 = 1024 blocks = 4/CU exactly)
    const size_t per_split = (size_t)HID * Nn * 4;   // 4 MB
    int SP = 1;
    while (SP < 16 && base + (size_t)(SP * 2) * per_split <= ws_size) SP *= 2;
    float* P = (float*)carve((size_t)SP * per_split);
    const int KCH = Nn / SP;

    // ---- converts ----
    {
        int n4 = Nn * Nn / 4;
        cvt_f32_bf16<<<dim3((n4 + 255) / 256), dim3(256), 0, stream>>>(
            (const float4*)S, (bf16x4*)Sb, n4);
        n4 = Nn * IN / 4;
        cvt_f32_bf16<<<dim3((n4 + 255) / 256), dim3(256), 0, stream>>>(
            (const float4*)X, (bf16x4*)Xb, n4);
    }
    cvt_transpose<<<dim3((IN * HID + 255) / 256), dim3(256), 0, stream>>>(W1, W1t, IN, HID);
    cvt_transpose<<<dim3((HID * HID + 255) / 256), dim3(256), 0, stream>>>(W2, W2t, HID, HID);
    cvt_transpose<<<dim3((HID * OUT + 255) / 256), dim3(256), 0, stream>>>(W3, W3t, HID, OUT);

    // S-GEMM: partials P[s][f][node]; A=Sb (ld 8192), B=Yt[f][8192]
    auto sgemm = [&](const __bf16* Bt, int F) {
        if (F == 128)
            gemm_rd<2, 8, 0><<<dim3(Nn / 128, 1, SP), dim3(256), 0, stream>>>(
                Sb, Bt, P, Nn, KCH, Nn, F);
        else
            gemm_rd<2, 4, 0><<<dim3(Nn / 128, 1, SP), dim3(256), 0, stream>>>(
                Sb, Bt, P, Nn, KCH, Nn, F);
    };
    auto reduceY = [&](__bf16* Y, int F) {
        int t4 = F * 2048;
        reduce_partials<<<dim3((t4 + 255) / 256), dim3(256), 0, stream>>>(
            P, Y, t4, SP, F * Nn);
    };

    // ---- layer 1 ----
    // Y0t = W1t @ Xb   (M=128, N=8192, K=512) — MF=1 tiles, 256 blocks
    gemm_rd<1, 4, 1><<<dim3(2, Nn / 64, 1), dim3(256), 0, stream>>>(
        W1t, Xb, Y0t, IN, IN, HID, Nn);
    sgemm(Y0t, HID);
    reduceY(Y1t, HID);
    sgemm(Y1t, HID);
    combine_out<1, 0><<<dim3(HID * 2048 / 256), dim3(256), 0, stream>>>(
        P, Y0t, Y1t, h1, b1, Act, HID, SP);

    // ---- layer 2 ----
    gemm_rd<1, 4, 1><<<dim3(2, Nn / 64, 1), dim3(256), 0, stream>>>(
        W2t, Act, Y0t, HID, HID, HID, Nn);
    sgemm(Y0t, HID);
    reduceY(Y1t, HID);
    sgemm(Y1t, HID);
    combine_out<1, 0><<<dim3(HID * 2048 / 256), dim3(256), 0, stream>>>(
        P, Y0t, Y1t, h2, b2, Act, HID, SP);

    // ---- layer 3 (F=64, fp32 out, no relu) ----
    gemm_rd<1, 4, 1><<<dim3(1, Nn / 64, 1), dim3(256), 0, stream>>>(
        W3t, Act, Y0t, HID, HID, OUT, Nn);
    sgemm(Y0t, OUT);
    reduceY(Y1t, OUT);
    sgemm(Y1t, OUT);
    combine_out<0, 1><<<dim3(OUT * 2048 / 256), dim3(256), 0, stream>>>(
        P, Y0t, Y1t, h3, b3, out, OUT, SP);

    (void)in_sizes; (void)n_in; (void)out_size;
}